// Round 1
// baseline (510.395 us; speedup 1.0000x reference)
//
#include <hip/hip_runtime.h>
#include <hip/hip_bf16.h>

// Problem: B=16, S=2048, H=1024
//   a = encoder_outputs (B,S,H) f32
//   projh[b,o] = sum_h h[b,h]*W[o,h] + bias[o]
//   scores[b,s] = sum_o relu( sum_h a[b,s,h]*W[o,H+h] + projh[b,o] ) * v[o]
//   weights = softmax_s(scores); context[b,h] = sum_s weights[b,s]*a[b,s,h]
// Outputs concat: context (16*1024 f32) then weights (16*2048 f32)

typedef __bf16 bf16x8 __attribute__((ext_vector_type(8)));
typedef float floatx4 __attribute__((ext_vector_type(4)));

#define BB 16
#define SS 2048
#define HH 1024
#define MM (BB * SS)

__device__ inline ushort f2bf(float x) {
    uint32_t u = __builtin_bit_cast(uint32_t, x);
    u += 0x7FFFu + ((u >> 16) & 1u);   // round-to-nearest-even
    return (ushort)(u >> 16);
}

// ---------------- projh: (16,1024) = h(16,1024) x W[:, :H]^T + bias ----------------
__global__ __launch_bounds__(256) void projh_kernel(
    const float* __restrict__ h, const float* __restrict__ W,
    const float* __restrict__ bias, float* __restrict__ projh)
{
    int b = blockIdx.x;
    int tid = threadIdx.x;
    __shared__ float hrow[HH];
    *(float4*)&hrow[tid * 4] = *(const float4*)(h + (size_t)b * HH + tid * 4);
    __syncthreads();
#pragma unroll
    for (int i = 0; i < 4; i++) {
        int o = tid + i * 256;
        const float* wr = W + (size_t)o * (2 * HH);   // row o, first half
        float sum = 0.f;
        for (int k = 0; k < HH; k += 4) {
            float4 wv = *(const float4*)(wr + k);
            sum += hrow[k] * wv.x + hrow[k + 1] * wv.y + hrow[k + 2] * wv.z + hrow[k + 3] * wv.w;
        }
        projh[b * HH + o] = sum + bias[o];
    }
}

// ---------------- main GEMM + fused relu*v reduction ----------------
// grid: (N/128=8, M/128=256); block 256 = 4 waves (2x2 wave grid, each 64x64)
__global__ __launch_bounds__(256) void gemm_scores_kernel(
    const float* __restrict__ A,      // (32768,1024) f32
    const float* __restrict__ W,      // (1024,2048) f32 — cols [1024,2048)
    const float* __restrict__ projh,  // (16,1024) f32
    const float* __restrict__ vW,     // (1024) f32
    float* __restrict__ scores)       // (32768) f32, pre-zeroed
{
    constexpr int BM = 128, BN = 128, BK = 32, LDT = BK + 8;  // +8 bf16 pad

    __shared__ __bf16 As[BM * LDT];
    __shared__ __bf16 Bs[BN * LDT];

    const int n0 = blockIdx.x * BN;
    const int m0 = blockIdx.y * BM;
    const int bidx = m0 >> 11;        // batch index (BM=128 divides S=2048)

    const int tid = threadIdx.x;
    const int lane = tid & 63;
    const int wave = tid >> 6;
    const int wm = (wave & 1) * 64;
    const int wn = (wave >> 1) * 64;
    const int quad = lane >> 4;
    const int l16 = lane & 15;

    floatx4 acc[4][4];
    const floatx4 z = {0.f, 0.f, 0.f, 0.f};
#pragma unroll
    for (int i = 0; i < 4; i++)
#pragma unroll
        for (int j = 0; j < 4; j++) acc[i][j] = z;

    // staging assignment: 4096 f32 per tile / 256 thr = 4 float4 each
    int rowT[4], colT[4];
#pragma unroll
    for (int i = 0; i < 4; i++) {
        int fi = tid + 256 * i;
        rowT[i] = fi >> 3;            // 8 float4 per 32-elem row
        colT[i] = (fi & 7) * 4;
    }

    for (int k0 = 0; k0 < HH; k0 += BK) {
        float4 av[4], bv[4];
#pragma unroll
        for (int i = 0; i < 4; i++) {
            av[i] = *(const float4*)(A + (size_t)(m0 + rowT[i]) * HH + k0 + colT[i]);
            bv[i] = *(const float4*)(W + (size_t)(n0 + rowT[i]) * (2 * HH) + HH + k0 + colT[i]);
        }
        __syncthreads();   // previous iter's frag reads done before overwrite
#pragma unroll
        for (int i = 0; i < 4; i++) {
            ushort4 ua = make_ushort4(f2bf(av[i].x), f2bf(av[i].y), f2bf(av[i].z), f2bf(av[i].w));
            ushort4 ub = make_ushort4(f2bf(bv[i].x), f2bf(bv[i].y), f2bf(bv[i].z), f2bf(bv[i].w));
            *(ushort4*)&As[rowT[i] * LDT + colT[i]] = ua;
            *(ushort4*)&Bs[rowT[i] * LDT + colT[i]] = ub;
        }
        __syncthreads();

        bf16x8 af[4], bf[4];
#pragma unroll
        for (int i = 0; i < 4; i++)
            af[i] = *(const bf16x8*)&As[(wm + i * 16 + l16) * LDT + quad * 8];
#pragma unroll
        for (int j = 0; j < 4; j++)
            bf[j] = *(const bf16x8*)&Bs[(wn + j * 16 + l16) * LDT + quad * 8];
#pragma unroll
        for (int i = 0; i < 4; i++)
#pragma unroll
            for (int j = 0; j < 4; j++)
                acc[i][j] = __builtin_amdgcn_mfma_f32_16x16x32_bf16(af[i], bf[j], acc[i][j], 0, 0, 0);
    }

    // epilogue: scores_partial[m] = sum_n relu(acc + projh[b,n]) * v[n]
    float ph[4], vv[4];
#pragma unroll
    for (int j = 0; j < 4; j++) {
        int ng = n0 + wn + j * 16 + l16;
        ph[j] = projh[bidx * HH + ng];
        vv[j] = vW[ng];
    }
#pragma unroll
    for (int i = 0; i < 4; i++) {
        float s[4] = {0.f, 0.f, 0.f, 0.f};
#pragma unroll
        for (int j = 0; j < 4; j++) {
#pragma unroll
            for (int r = 0; r < 4; r++) {
                float e = acc[i][j][r] + ph[j];
                e = e > 0.f ? e : 0.f;
                s[r] += e * vv[j];
            }
        }
#pragma unroll
        for (int r = 0; r < 4; r++) {
            s[r] += __shfl_xor(s[r], 1);
            s[r] += __shfl_xor(s[r], 2);
            s[r] += __shfl_xor(s[r], 4);
            s[r] += __shfl_xor(s[r], 8);
        }
        if (l16 == 0) {
#pragma unroll
            for (int r = 0; r < 4; r++) {
                int mg = m0 + wm + i * 16 + quad * 4 + r;   // D row = quad*4 + reg
                atomicAdd(&scores[mg], s[r]);
            }
        }
    }
}

// ---------------- softmax over S per batch ----------------
__global__ __launch_bounds__(256) void softmax_kernel(
    const float* __restrict__ scores, float* __restrict__ wout)
{
    int b = blockIdx.x;
    int tid = threadIdx.x;
    const float* row = scores + b * SS;
    float x[8];
    float mx = -1e30f;
#pragma unroll
    for (int i = 0; i < 8; i++) { x[i] = row[tid + i * 256]; mx = fmaxf(mx, x[i]); }
#pragma unroll
    for (int off = 32; off; off >>= 1) mx = fmaxf(mx, __shfl_xor(mx, off));
    __shared__ float redm[4], reds[4];
    if ((tid & 63) == 0) redm[tid >> 6] = mx;
    __syncthreads();
    mx = fmaxf(fmaxf(redm[0], redm[1]), fmaxf(redm[2], redm[3]));
    float sum = 0.f;
#pragma unroll
    for (int i = 0; i < 8; i++) { x[i] = __expf(x[i] - mx); sum += x[i]; }
#pragma unroll
    for (int off = 32; off; off >>= 1) sum += __shfl_xor(sum, off);
    if ((tid & 63) == 0) reds[tid >> 6] = sum;
    __syncthreads();
    float inv = 1.0f / (reds[0] + reds[1] + reds[2] + reds[3]);
#pragma unroll
    for (int i = 0; i < 8; i++) wout[b * SS + tid + i * 256] = x[i] * inv;
}

// ---------------- context = weights @ a ----------------
// grid: 16 b * 16 s-chunks; 256 threads * float4 = 1024 h
__global__ __launch_bounds__(256) void context_kernel(
    const float* __restrict__ A, const float* __restrict__ wgt, float* __restrict__ ctx)
{
    int b = blockIdx.x >> 4;
    int sc = blockIdx.x & 15;
    int tid = threadIdx.x;
    const float* arow = A + ((size_t)b * SS + sc * 128) * HH + tid * 4;
    const float* wrow = wgt + b * SS + sc * 128;
    float4 acc = make_float4(0.f, 0.f, 0.f, 0.f);
#pragma unroll 4
    for (int s = 0; s < 128; s++) {
        float w = wrow[s];
        float4 v = *(const float4*)(arow + (size_t)s * HH);
        acc.x += w * v.x; acc.y += w * v.y; acc.z += w * v.z; acc.w += w * v.w;
    }
    float* o = ctx + b * HH + tid * 4;
    atomicAdd(o + 0, acc.x);
    atomicAdd(o + 1, acc.y);
    atomicAdd(o + 2, acc.z);
    atomicAdd(o + 3, acc.w);
}

extern "C" void kernel_launch(void* const* d_in, const int* in_sizes, int n_in,
                              void* d_out, int out_size, void* d_ws, size_t ws_size,
                              hipStream_t stream) {
    const float* h    = (const float*)d_in[0];
    // d_in[1] = c (unused by reference)
    const float* a    = (const float*)d_in[2];
    const float* W    = (const float*)d_in[3];
    const float* bias = (const float*)d_in[4];
    const float* vW   = (const float*)d_in[5];
    float* out = (float*)d_out;

    float* projh  = (float*)d_ws;            // 16*1024 f32
    float* scores = projh + BB * HH;         // 32768 f32

    // zero atomics targets (ws/out are poisoned 0xAA before every launch)
    hipMemsetAsync(scores, 0, (size_t)MM * sizeof(float), stream);
    hipMemsetAsync(out, 0, (size_t)BB * HH * sizeof(float), stream);

    projh_kernel<<<BB, 256, 0, stream>>>(h, W, bias, projh);
    gemm_scores_kernel<<<dim3(HH / 128, MM / 128), 256, 0, stream>>>(a, W, projh, vW, scores);
    softmax_kernel<<<BB, 256, 0, stream>>>(scores, out + BB * HH);
    context_kernel<<<BB * 16, 256, 0, stream>>>(a, out + BB * HH, out);
}

// Round 2
// 340.711 us; speedup vs baseline: 1.4980x; 1.4980x over previous
//
#include <hip/hip_runtime.h>
#include <hip/hip_bf16.h>

// Problem: B=16, S=2048, H=1024
//   a = encoder_outputs (B,S,H) f32
//   projh[b,o] = sum_h h[b,h]*W[o,h] + bias[o]
//   scores[b,s] = sum_o relu( sum_h a[b,s,h]*W[o,H+h] + projh[b,o] ) * v[o]
//   weights = softmax_s(scores); context[b,h] = sum_s weights[b,s]*a[b,s,h]
// Outputs concat: context (16*1024 f32) then weights (16*2048 f32)

typedef __bf16 bf16x8 __attribute__((ext_vector_type(8)));
typedef float floatx4 __attribute__((ext_vector_type(4)));

#define BB 16
#define SS 2048
#define HH 1024
#define MM (BB * SS)

#define GLB(p) ((const __attribute__((address_space(1))) void*)(p))
#define LDSP(p) ((__attribute__((address_space(3))) void*)(p))

__device__ inline ushort f2bf(float x) {
    uint32_t u = __builtin_bit_cast(uint32_t, x);
    u += 0x7FFFu + ((u >> 16) & 1u);   // round-to-nearest-even
    return (ushort)(u >> 16);
}

// ---------------- f32 -> bf16 bulk convert (A: 33.5M elems) ----------------
__global__ __launch_bounds__(256) void convert_A_kernel(
    const float* __restrict__ src, __bf16* __restrict__ dst)
{
    size_t i = (size_t)blockIdx.x * 256 + threadIdx.x;   // 8-elem group
    const float* s = src + i * 8;
    float4 a = *(const float4*)(s);
    float4 b = *(const float4*)(s + 4);
    union { ushort u[8]; uint4 v; } p;
    p.u[0] = f2bf(a.x); p.u[1] = f2bf(a.y); p.u[2] = f2bf(a.z); p.u[3] = f2bf(a.w);
    p.u[4] = f2bf(b.x); p.u[5] = f2bf(b.y); p.u[6] = f2bf(b.z); p.u[7] = f2bf(b.w);
    *(uint4*)(dst + i * 8) = p.v;
}

// ---------------- W[:, H:2H] -> bf16 Wb (N=1024 x K=1024) ----------------
__global__ __launch_bounds__(256) void convert_W_kernel(
    const float* __restrict__ W, __bf16* __restrict__ Wb)
{
    int i = blockIdx.x * 256 + threadIdx.x;   // 8-elem group, 131072 total
    int o = i >> 7;                // row (128 groups per 1024-col row)
    int k = (i & 127) * 8;
    const float* s = W + (size_t)o * (2 * HH) + HH + k;
    float4 a = *(const float4*)(s);
    float4 b = *(const float4*)(s + 4);
    union { ushort u[8]; uint4 v; } p;
    p.u[0] = f2bf(a.x); p.u[1] = f2bf(a.y); p.u[2] = f2bf(a.z); p.u[3] = f2bf(a.w);
    p.u[4] = f2bf(b.x); p.u[5] = f2bf(b.y); p.u[6] = f2bf(b.z); p.u[7] = f2bf(b.w);
    *(uint4*)(Wb + (size_t)o * HH + k) = p.v;
}

// ---------------- projh: (16,1024) = h(16,1024) x W[:, :H]^T + bias ----------------
// grid = 16 b x 16 o-chunks (64 outputs each); 4 lanes k-split per output.
__global__ __launch_bounds__(256) void projh_kernel(
    const float* __restrict__ h, const float* __restrict__ W,
    const float* __restrict__ bias, float* __restrict__ projh)
{
    int b = blockIdx.x >> 4;
    int oc = blockIdx.x & 15;
    int tid = threadIdx.x;
    __shared__ float hrow[HH];
    *(float4*)&hrow[tid * 4] = *(const float4*)(h + (size_t)b * HH + tid * 4);
    __syncthreads();
    int ol = tid >> 2;           // 0..63
    int kq = tid & 3;            // 0..3 (k quarter)
    int o = oc * 64 + ol;
    const float* wr = W + (size_t)o * (2 * HH) + kq * 256;
    const float* hb = hrow + kq * 256;
    float sum = 0.f;
    for (int k = 0; k < 256; k += 4) {
        float4 wv = *(const float4*)(wr + k);
        sum += hb[k] * wv.x + hb[k + 1] * wv.y + hb[k + 2] * wv.z + hb[k + 3] * wv.w;
    }
    sum += __shfl_xor(sum, 1);
    sum += __shfl_xor(sum, 2);
    if (kq == 0) projh[b * HH + o] = sum + bias[o];
}

// ---------------- main GEMM (bf16, global_load_lds staging) + fused relu*v ----------------
// grid: (N/128=8, M/128=256); block 256 = 4 waves (2x2 wave grid, each 64x64)
// LDS tiles are stored in a chunk-swizzled layout:
//   chunk c (16B = 8 bf16) holds tile element (row = 2u + (jj>>2), col = (jj&3)*8)
//   where u = c>>3, jj = (c&7) ^ (u&7).
//   The global gather computes the inverse; the frag ds_read_b128 for logical
//   (row, q) uses c = (row>>1)*8 + ((((row&1)<<2)|q) ^ ((row>>1)&7)), which
//   spreads each 8-lane group uniformly over all 8 bank-quads.
__global__ __launch_bounds__(256) void gemm_scores_kernel(
    const __bf16* __restrict__ Ab,    // (32768,1024) bf16
    const __bf16* __restrict__ Wb,    // (1024,1024) bf16 (cols H..2H of W)
    const float* __restrict__ projh,  // (16,1024) f32
    const float* __restrict__ vW,     // (1024) f32
    float* __restrict__ scores)       // (32768) f32, pre-zeroed
{
    constexpr int BM = 128, BN = 128, BK = 32;

    __shared__ __bf16 As[BM * BK];    // 8 KB, swizzled chunk layout
    __shared__ __bf16 Bs[BN * BK];

    const int n0 = blockIdx.x * BN;
    const int m0 = blockIdx.y * BM;
    const int bidx = m0 >> 11;        // batch index (BM=128 divides S=2048)

    const int tid = threadIdx.x;
    const int lane = tid & 63;
    const int wave = tid >> 6;
    const int wm = (wave & 1) * 64;
    const int wn = (wave >> 1) * 64;
    const int quad = lane >> 4;
    const int l16 = lane & 15;

    floatx4 acc[4][4];
    const floatx4 z = {0.f, 0.f, 0.f, 0.f};
#pragma unroll
    for (int i = 0; i < 4; i++)
#pragma unroll
        for (int j = 0; j < 4; j++) acc[i][j] = z;

    // ---- staging precompute: 4 issues (0,1 -> As parts; 2,3 -> Bs parts) ----
    int g_row[4], g_col[4];
#pragma unroll
    for (int is = 0; is < 4; is++) {
        int part = is & 1;
        int c = part * 256 + tid;       // chunk in [0,512)
        int u = c >> 3, j = c & 7;
        int jj = j ^ (u & 7);
        g_row[is] = u * 2 + (jj >> 2);
        g_col[is] = (jj & 3) * 8;
    }
    const __bf16* gA0 = Ab + (size_t)(m0 + g_row[0]) * HH + g_col[0];
    const __bf16* gA1 = Ab + (size_t)(m0 + g_row[1]) * HH + g_col[1];
    const __bf16* gB0 = Wb + (size_t)(n0 + g_row[2]) * HH + g_col[2];
    const __bf16* gB1 = Wb + (size_t)(n0 + g_row[3]) * HH + g_col[3];
    // wave-uniform LDS bases (chunk base = part*256 + wave*64 -> elem = *8)
    __bf16* lA0 = As + (size_t)wave * 512;
    __bf16* lA1 = As + 2048 + (size_t)wave * 512;
    __bf16* lB0 = Bs + (size_t)wave * 512;
    __bf16* lB1 = Bs + 2048 + (size_t)wave * 512;

    // ---- fragment LDS addresses (k-invariant) ----
    const __bf16* aaddr[4];
    const __bf16* baddr[4];
#pragma unroll
    for (int i = 0; i < 4; i++) {
        int frow = wm + i * 16 + l16;
        int u = frow >> 1;
        int cc = u * 8 + (((((frow & 1) << 2) | quad)) ^ (u & 7));
        aaddr[i] = &As[cc * 8];
        frow = wn + i * 16 + l16;
        u = frow >> 1;
        cc = u * 8 + (((((frow & 1) << 2) | quad)) ^ (u & 7));
        baddr[i] = &Bs[cc * 8];
    }

    for (int k0 = 0; k0 < HH; k0 += BK) {
        __syncthreads();   // all waves done reading previous tile
        __builtin_amdgcn_global_load_lds(GLB(gA0 + k0), LDSP(lA0), 16, 0, 0);
        __builtin_amdgcn_global_load_lds(GLB(gA1 + k0), LDSP(lA1), 16, 0, 0);
        __builtin_amdgcn_global_load_lds(GLB(gB0 + k0), LDSP(lB0), 16, 0, 0);
        __builtin_amdgcn_global_load_lds(GLB(gB1 + k0), LDSP(lB1), 16, 0, 0);
        __syncthreads();   // loads landed (barrier drains vmcnt)

        bf16x8 af[4], bf[4];
#pragma unroll
        for (int i = 0; i < 4; i++) af[i] = *(const bf16x8*)aaddr[i];
#pragma unroll
        for (int j = 0; j < 4; j++) bf[j] = *(const bf16x8*)baddr[j];
#pragma unroll
        for (int i = 0; i < 4; i++)
#pragma unroll
            for (int j = 0; j < 4; j++)
                acc[i][j] = __builtin_amdgcn_mfma_f32_16x16x32_bf16(af[i], bf[j], acc[i][j], 0, 0, 0);
    }

    // epilogue: scores_partial[m] = sum_n relu(acc + projh[b,n]) * v[n]
    float ph[4], vv[4];
#pragma unroll
    for (int j = 0; j < 4; j++) {
        int ng = n0 + wn + j * 16 + l16;
        ph[j] = projh[bidx * HH + ng];
        vv[j] = vW[ng];
    }
#pragma unroll
    for (int i = 0; i < 4; i++) {
        float s[4] = {0.f, 0.f, 0.f, 0.f};
#pragma unroll
        for (int j = 0; j < 4; j++) {
#pragma unroll
            for (int r = 0; r < 4; r++) {
                float e = acc[i][j][r] + ph[j];
                e = e > 0.f ? e : 0.f;
                s[r] += e * vv[j];
            }
        }
#pragma unroll
        for (int r = 0; r < 4; r++) {
            s[r] += __shfl_xor(s[r], 1);
            s[r] += __shfl_xor(s[r], 2);
            s[r] += __shfl_xor(s[r], 4);
            s[r] += __shfl_xor(s[r], 8);
        }
        if (l16 == 0) {
#pragma unroll
            for (int r = 0; r < 4; r++) {
                int mg = m0 + wm + i * 16 + quad * 4 + r;   // D row = quad*4 + reg
                atomicAdd(&scores[mg], s[r]);
            }
        }
    }
}

// ---------------- fallback GEMM (f32 staging, used if ws too small) ----------------
__global__ __launch_bounds__(256) void gemm_scores_f32_kernel(
    const float* __restrict__ A, const float* __restrict__ W,
    const float* __restrict__ projh, const float* __restrict__ vW,
    float* __restrict__ scores)
{
    constexpr int BM = 128, BN = 128, BK = 32, LDT = BK + 8;
    __shared__ __bf16 As[BM * LDT];
    __shared__ __bf16 Bs[BN * LDT];
    const int n0 = blockIdx.x * BN;
    const int m0 = blockIdx.y * BM;
    const int bidx = m0 >> 11;
    const int tid = threadIdx.x;
    const int lane = tid & 63;
    const int wave = tid >> 6;
    const int wm = (wave & 1) * 64;
    const int wn = (wave >> 1) * 64;
    const int quad = lane >> 4;
    const int l16 = lane & 15;
    floatx4 acc[4][4];
    const floatx4 z = {0.f, 0.f, 0.f, 0.f};
#pragma unroll
    for (int i = 0; i < 4; i++)
#pragma unroll
        for (int j = 0; j < 4; j++) acc[i][j] = z;
    int rowT[4], colT[4];
#pragma unroll
    for (int i = 0; i < 4; i++) {
        int fi = tid + 256 * i;
        rowT[i] = fi >> 3;
        colT[i] = (fi & 7) * 4;
    }
    for (int k0 = 0; k0 < HH; k0 += BK) {
        float4 av[4], bv[4];
#pragma unroll
        for (int i = 0; i < 4; i++) {
            av[i] = *(const float4*)(A + (size_t)(m0 + rowT[i]) * HH + k0 + colT[i]);
            bv[i] = *(const float4*)(W + (size_t)(n0 + rowT[i]) * (2 * HH) + HH + k0 + colT[i]);
        }
        __syncthreads();
#pragma unroll
        for (int i = 0; i < 4; i++) {
            ushort4 ua = make_ushort4(f2bf(av[i].x), f2bf(av[i].y), f2bf(av[i].z), f2bf(av[i].w));
            ushort4 ub = make_ushort4(f2bf(bv[i].x), f2bf(bv[i].y), f2bf(bv[i].z), f2bf(bv[i].w));
            *(ushort4*)&As[rowT[i] * LDT + colT[i]] = ua;
            *(ushort4*)&Bs[rowT[i] * LDT + colT[i]] = ub;
        }
        __syncthreads();
        bf16x8 af[4], bf[4];
#pragma unroll
        for (int i = 0; i < 4; i++)
            af[i] = *(const bf16x8*)&As[(wm + i * 16 + l16) * LDT + quad * 8];
#pragma unroll
        for (int j = 0; j < 4; j++)
            bf[j] = *(const bf16x8*)&Bs[(wn + j * 16 + l16) * LDT + quad * 8];
#pragma unroll
        for (int i = 0; i < 4; i++)
#pragma unroll
            for (int j = 0; j < 4; j++)
                acc[i][j] = __builtin_amdgcn_mfma_f32_16x16x32_bf16(af[i], bf[j], acc[i][j], 0, 0, 0);
    }
    float ph[4], vv[4];
#pragma unroll
    for (int j = 0; j < 4; j++) {
        int ng = n0 + wn + j * 16 + l16;
        ph[j] = projh[bidx * HH + ng];
        vv[j] = vW[ng];
    }
#pragma unroll
    for (int i = 0; i < 4; i++) {
        float s[4] = {0.f, 0.f, 0.f, 0.f};
#pragma unroll
        for (int j = 0; j < 4; j++) {
#pragma unroll
            for (int r = 0; r < 4; r++) {
                float e = acc[i][j][r] + ph[j];
                e = e > 0.f ? e : 0.f;
                s[r] += e * vv[j];
            }
        }
#pragma unroll
        for (int r = 0; r < 4; r++) {
            s[r] += __shfl_xor(s[r], 1);
            s[r] += __shfl_xor(s[r], 2);
            s[r] += __shfl_xor(s[r], 4);
            s[r] += __shfl_xor(s[r], 8);
        }
        if (l16 == 0) {
#pragma unroll
            for (int r = 0; r < 4; r++) {
                int mg = m0 + wm + i * 16 + quad * 4 + r;
                atomicAdd(&scores[mg], s[r]);
            }
        }
    }
}

// ---------------- softmax over S per batch ----------------
__global__ __launch_bounds__(256) void softmax_kernel(
    const float* __restrict__ scores, float* __restrict__ wout)
{
    int b = blockIdx.x;
    int tid = threadIdx.x;
    const float* row = scores + b * SS;
    float x[8];
    float mx = -1e30f;
#pragma unroll
    for (int i = 0; i < 8; i++) { x[i] = row[tid + i * 256]; mx = fmaxf(mx, x[i]); }
#pragma unroll
    for (int off = 32; off; off >>= 1) mx = fmaxf(mx, __shfl_xor(mx, off));
    __shared__ float redm[4], reds[4];
    if ((tid & 63) == 0) redm[tid >> 6] = mx;
    __syncthreads();
    mx = fmaxf(fmaxf(redm[0], redm[1]), fmaxf(redm[2], redm[3]));
    float sum = 0.f;
#pragma unroll
    for (int i = 0; i < 8; i++) { x[i] = __expf(x[i] - mx); sum += x[i]; }
#pragma unroll
    for (int off = 32; off; off >>= 1) sum += __shfl_xor(sum, off);
    if ((tid & 63) == 0) reds[tid >> 6] = sum;
    __syncthreads();
    float inv = 1.0f / (reds[0] + reds[1] + reds[2] + reds[3]);
#pragma unroll
    for (int i = 0; i < 8; i++) wout[b * SS + tid + i * 256] = x[i] * inv;
}

// ---------------- context = weights @ a ----------------
__global__ __launch_bounds__(256) void context_kernel(
    const float* __restrict__ A, const float* __restrict__ wgt, float* __restrict__ ctx)
{
    int b = blockIdx.x >> 4;
    int sc = blockIdx.x & 15;
    int tid = threadIdx.x;
    const float* arow = A + ((size_t)b * SS + sc * 128) * HH + tid * 4;
    const float* wrow = wgt + b * SS + sc * 128;
    float4 acc = make_float4(0.f, 0.f, 0.f, 0.f);
#pragma unroll 4
    for (int s = 0; s < 128; s++) {
        float w = wrow[s];
        float4 v = *(const float4*)(arow + (size_t)s * HH);
        acc.x += w * v.x; acc.y += w * v.y; acc.z += w * v.z; acc.w += w * v.w;
    }
    float* o = ctx + b * HH + tid * 4;
    atomicAdd(o + 0, acc.x);
    atomicAdd(o + 1, acc.y);
    atomicAdd(o + 2, acc.z);
    atomicAdd(o + 3, acc.w);
}

extern "C" void kernel_launch(void* const* d_in, const int* in_sizes, int n_in,
                              void* d_out, int out_size, void* d_ws, size_t ws_size,
                              hipStream_t stream) {
    const float* h    = (const float*)d_in[0];
    // d_in[1] = c (unused by reference)
    const float* a    = (const float*)d_in[2];
    const float* W    = (const float*)d_in[3];
    const float* bias = (const float*)d_in[4];
    const float* vW   = (const float*)d_in[5];
    float* out = (float*)d_out;

    float* projh  = (float*)d_ws;              // 16384 f32  (64 KB)
    float* scores = projh + BB * HH;           // 32768 f32  (128 KB)
    __bf16* Wb = (__bf16*)(scores + MM);       // 1M bf16    (2 MB)
    __bf16* Ab = Wb + (size_t)HH * HH;         // 33.5M bf16 (67.1 MB)
    const size_t need = (size_t)(BB * HH + MM) * 4 + (size_t)HH * HH * 2
                      + (size_t)MM * HH * 2;

    hipMemsetAsync(scores, 0, (size_t)MM * sizeof(float), stream);
    hipMemsetAsync(out, 0, (size_t)BB * HH * sizeof(float), stream);

    projh_kernel<<<BB * 16, 256, 0, stream>>>(h, W, bias, projh);

    if (ws_size >= need) {
        convert_A_kernel<<<(MM * HH / 8) / 256, 256, 0, stream>>>(a, Ab);
        convert_W_kernel<<<(HH * HH / 8) / 256, 256, 0, stream>>>(W, Wb);
        gemm_scores_kernel<<<dim3(HH / 128, MM / 128), 256, 0, stream>>>(Ab, Wb, projh, vW, scores);
    } else {
        gemm_scores_f32_kernel<<<dim3(HH / 128, MM / 128), 256, 0, stream>>>(a, W, projh, vW, scores);
    }

    softmax_kernel<<<BB, 256, 0, stream>>>(scores, out + BB * HH);
    context_kernel<<<BB * 16, 256, 0, stream>>>(a, out + BB * HH, out);
}

// Round 3
// 323.671 us; speedup vs baseline: 1.5769x; 1.0526x over previous
//
#include <hip/hip_runtime.h>
#include <hip/hip_bf16.h>

// Problem: B=16, S=2048, H=1024
//   a = encoder_outputs (B,S,H) f32
//   projh[b,o] = sum_h h[b,h]*W[o,h] + bias[o]
//   scores[b,s] = sum_o relu( sum_h a[b,s,h]*W[o,H+h] + projh[b,o] ) * v[o]
//   weights = softmax_s(scores); context[b,h] = sum_s weights[b,s]*a[b,s,h]
// Outputs concat: context (16*1024 f32) then weights (16*2048 f32)

typedef __bf16 bf16x8 __attribute__((ext_vector_type(8)));
typedef float floatx4 __attribute__((ext_vector_type(4)));

#define BB 16
#define SS 2048
#define HH 1024
#define MM (BB * SS)

#define GLB(p) ((const __attribute__((address_space(1))) void*)(p))
#define LDSP(p) ((__attribute__((address_space(3))) void*)(p))

__device__ inline ushort f2bf(float x) {
    uint32_t u = __builtin_bit_cast(uint32_t, x);
    u += 0x7FFFu + ((u >> 16) & 1u);   // round-to-nearest-even
    return (ushort)(u >> 16);
}

// ---------------- f32 -> bf16 bulk convert (A: 33.5M elems) ----------------
__global__ __launch_bounds__(256) void convert_A_kernel(
    const float* __restrict__ src, __bf16* __restrict__ dst)
{
    size_t i = (size_t)blockIdx.x * 256 + threadIdx.x;   // 8-elem group
    const float* s = src + i * 8;
    float4 a = *(const float4*)(s);
    float4 b = *(const float4*)(s + 4);
    union { ushort u[8]; uint4 v; } p;
    p.u[0] = f2bf(a.x); p.u[1] = f2bf(a.y); p.u[2] = f2bf(a.z); p.u[3] = f2bf(a.w);
    p.u[4] = f2bf(b.x); p.u[5] = f2bf(b.y); p.u[6] = f2bf(b.z); p.u[7] = f2bf(b.w);
    *(uint4*)(dst + i * 8) = p.v;
}

// ---------------- prep: projh (blocks 0..255) + convert_W (256..319) + zero (320..335) ----
__global__ __launch_bounds__(256) void prep_kernel(
    const float* __restrict__ h, const float* __restrict__ W,
    const float* __restrict__ bias, float* __restrict__ projh,
    __bf16* __restrict__ Wb, float* __restrict__ scores, float* __restrict__ ctx)
{
    int bid = blockIdx.x;
    int tid = threadIdx.x;
    if (bid < 256) {
        // projh: (16,1024) = h(16,1024) x W[:, :H]^T + bias
        int b = bid >> 4;
        int oc = bid & 15;
        __shared__ float hrow[HH];
        *(float4*)&hrow[tid * 4] = *(const float4*)(h + (size_t)b * HH + tid * 4);
        __syncthreads();
        int ol = tid >> 2;           // 0..63
        int kq = tid & 3;            // 0..3 (k quarter)
        int o = oc * 64 + ol;
        const float* wr = W + (size_t)o * (2 * HH) + kq * 256;
        const float* hb = hrow + kq * 256;
        float sum = 0.f;
        for (int k = 0; k < 256; k += 4) {
            float4 wv = *(const float4*)(wr + k);
            sum += hb[k] * wv.x + hb[k + 1] * wv.y + hb[k + 2] * wv.z + hb[k + 3] * wv.w;
        }
        sum += __shfl_xor(sum, 1);
        sum += __shfl_xor(sum, 2);
        if (kq == 0) projh[b * HH + o] = sum + bias[o];
    } else if (bid < 320) {
        // convert W[:, H:2H] -> Wb (1024x1024 bf16): 64 blocks x 256 thr x 8 groups x 8 elems
        int cb = bid - 256;
#pragma unroll
        for (int j = 0; j < 8; j++) {
            int g = cb * 2048 + tid + j * 256;
            int o = g >> 7;
            int k = (g & 127) * 8;
            const float* s = W + (size_t)o * (2 * HH) + HH + k;
            float4 a = *(const float4*)(s);
            float4 b2 = *(const float4*)(s + 4);
            union { ushort u[8]; uint4 v; } p;
            p.u[0] = f2bf(a.x); p.u[1] = f2bf(a.y); p.u[2] = f2bf(a.z); p.u[3] = f2bf(a.w);
            p.u[4] = f2bf(b2.x); p.u[5] = f2bf(b2.y); p.u[6] = f2bf(b2.z); p.u[7] = f2bf(b2.w);
            *(uint4*)(Wb + (size_t)o * HH + k) = p.v;
        }
    } else {
        // zero scores (32768 f32) and ctx (16384 f32): 16 blocks
        int zb = bid - 320;
        float4 z = make_float4(0.f, 0.f, 0.f, 0.f);
        float* sp = scores + zb * 2048 + tid * 8;
        *(float4*)(sp) = z;
        *(float4*)(sp + 4) = z;
        *(float4*)(ctx + zb * 1024 + tid * 4) = z;
    }
}

// ---------------- main GEMM (bf16, global_load_lds staging) + fused relu*v ----------------
// 1D grid of 2048 blocks, remapped so the 8 N-sibling blocks of each M-row have
// bids {c, c+8, ..., c+56} within a 64-block group: same XCD (round-robin bid%8)
// AND co-resident -> A tile is fetched from HBM once, staged from L2 thereafter.
// LDS tiles use a chunk-swizzled layout (see round-2 notes): zero bank conflicts.
__global__ __launch_bounds__(256) void gemm_scores_kernel(
    const __bf16* __restrict__ Ab,    // (32768,1024) bf16
    const __bf16* __restrict__ Wb,    // (1024,1024) bf16 (cols H..2H of W)
    const float* __restrict__ projh,  // (16,1024) f32
    const float* __restrict__ vW,     // (1024) f32
    float* __restrict__ scores)       // (32768) f32, pre-zeroed
{
    constexpr int BM = 128, BN = 128, BK = 32;

    __shared__ __bf16 As[BM * BK];    // 8 KB, swizzled chunk layout
    __shared__ __bf16 Bs[BN * BK];

    const int bid = blockIdx.x;
    const int grp = bid >> 6;           // 32 groups of 64 blocks
    const int r   = bid & 63;
    const int n0 = (r >> 3) * BN;       // 8 N-blocks
    const int my = grp * 8 + (r & 7);   // M-row index in [0,256)
    const int m0 = my * BM;
    const int bidx = m0 >> 11;          // batch index (BM=128 divides S=2048)

    const int tid = threadIdx.x;
    const int lane = tid & 63;
    const int wave = tid >> 6;
    const int wm = (wave & 1) * 64;
    const int wn = (wave >> 1) * 64;
    const int quad = lane >> 4;
    const int l16 = lane & 15;

    floatx4 acc[4][4];
    const floatx4 z = {0.f, 0.f, 0.f, 0.f};
#pragma unroll
    for (int i = 0; i < 4; i++)
#pragma unroll
        for (int j = 0; j < 4; j++) acc[i][j] = z;

    // ---- staging precompute: 4 issues (0,1 -> As parts; 2,3 -> Bs parts) ----
    int g_row[4], g_col[4];
#pragma unroll
    for (int is = 0; is < 4; is++) {
        int part = is & 1;
        int c = part * 256 + tid;       // chunk in [0,512)
        int u = c >> 3, j = c & 7;
        int jj = j ^ (u & 7);
        g_row[is] = u * 2 + (jj >> 2);
        g_col[is] = (jj & 3) * 8;
    }
    const __bf16* gA0 = Ab + (size_t)(m0 + g_row[0]) * HH + g_col[0];
    const __bf16* gA1 = Ab + (size_t)(m0 + g_row[1]) * HH + g_col[1];
    const __bf16* gB0 = Wb + (size_t)(n0 + g_row[2]) * HH + g_col[2];
    const __bf16* gB1 = Wb + (size_t)(n0 + g_row[3]) * HH + g_col[3];
    __bf16* lA0 = As + (size_t)wave * 512;
    __bf16* lA1 = As + 2048 + (size_t)wave * 512;
    __bf16* lB0 = Bs + (size_t)wave * 512;
    __bf16* lB1 = Bs + 2048 + (size_t)wave * 512;

    // ---- fragment LDS addresses (k-invariant) ----
    const __bf16* aaddr[4];
    const __bf16* baddr[4];
#pragma unroll
    for (int i = 0; i < 4; i++) {
        int frow = wm + i * 16 + l16;
        int u = frow >> 1;
        int cc = u * 8 + (((((frow & 1) << 2) | quad)) ^ (u & 7));
        aaddr[i] = &As[cc * 8];
        frow = wn + i * 16 + l16;
        u = frow >> 1;
        cc = u * 8 + (((((frow & 1) << 2) | quad)) ^ (u & 7));
        baddr[i] = &Bs[cc * 8];
    }

    for (int k0 = 0; k0 < HH; k0 += BK) {
        __syncthreads();   // all waves done reading previous tile
        __builtin_amdgcn_global_load_lds(GLB(gA0 + k0), LDSP(lA0), 16, 0, 0);
        __builtin_amdgcn_global_load_lds(GLB(gA1 + k0), LDSP(lA1), 16, 0, 0);
        __builtin_amdgcn_global_load_lds(GLB(gB0 + k0), LDSP(lB0), 16, 0, 0);
        __builtin_amdgcn_global_load_lds(GLB(gB1 + k0), LDSP(lB1), 16, 0, 0);
        __syncthreads();   // loads landed (barrier drains vmcnt)

        bf16x8 af[4], bf[4];
#pragma unroll
        for (int i = 0; i < 4; i++) af[i] = *(const bf16x8*)aaddr[i];
#pragma unroll
        for (int j = 0; j < 4; j++) bf[j] = *(const bf16x8*)baddr[j];
#pragma unroll
        for (int i = 0; i < 4; i++)
#pragma unroll
            for (int j = 0; j < 4; j++)
                acc[i][j] = __builtin_amdgcn_mfma_f32_16x16x32_bf16(af[i], bf[j], acc[i][j], 0, 0, 0);
    }

    // epilogue: scores_partial[m] = sum_n relu(acc + projh[b,n]) * v[n]
    float ph[4], vv[4];
#pragma unroll
    for (int j = 0; j < 4; j++) {
        int ng = n0 + wn + j * 16 + l16;
        ph[j] = projh[bidx * HH + ng];
        vv[j] = vW[ng];
    }
#pragma unroll
    for (int i = 0; i < 4; i++) {
        float s[4] = {0.f, 0.f, 0.f, 0.f};
#pragma unroll
        for (int j = 0; j < 4; j++) {
#pragma unroll
            for (int r2 = 0; r2 < 4; r2++) {
                float e = acc[i][j][r2] + ph[j];
                e = e > 0.f ? e : 0.f;
                s[r2] += e * vv[j];
            }
        }
#pragma unroll
        for (int r2 = 0; r2 < 4; r2++) {
            s[r2] += __shfl_xor(s[r2], 1);
            s[r2] += __shfl_xor(s[r2], 2);
            s[r2] += __shfl_xor(s[r2], 4);
            s[r2] += __shfl_xor(s[r2], 8);
        }
        if (l16 == 0) {
#pragma unroll
            for (int r2 = 0; r2 < 4; r2++) {
                int mg = m0 + wm + i * 16 + quad * 4 + r2;   // D row = quad*4 + reg
                atomicAdd(&scores[mg], s[r2]);
            }
        }
    }
}

// ---------------- fallback GEMM (f32 staging, used if ws too small) ----------------
__global__ __launch_bounds__(256) void gemm_scores_f32_kernel(
    const float* __restrict__ A, const float* __restrict__ W,
    const float* __restrict__ projh, const float* __restrict__ vW,
    float* __restrict__ scores)
{
    constexpr int BM = 128, BN = 128, BK = 32, LDT = BK + 8;
    __shared__ __bf16 As[BM * LDT];
    __shared__ __bf16 Bs[BN * LDT];
    const int n0 = blockIdx.x * BN;
    const int m0 = blockIdx.y * BM;
    const int bidx = m0 >> 11;
    const int tid = threadIdx.x;
    const int lane = tid & 63;
    const int wave = tid >> 6;
    const int wm = (wave & 1) * 64;
    const int wn = (wave >> 1) * 64;
    const int quad = lane >> 4;
    const int l16 = lane & 15;
    floatx4 acc[4][4];
    const floatx4 z = {0.f, 0.f, 0.f, 0.f};
#pragma unroll
    for (int i = 0; i < 4; i++)
#pragma unroll
        for (int j = 0; j < 4; j++) acc[i][j] = z;
    int rowT[4], colT[4];
#pragma unroll
    for (int i = 0; i < 4; i++) {
        int fi = tid + 256 * i;
        rowT[i] = fi >> 3;
        colT[i] = (fi & 7) * 4;
    }
    for (int k0 = 0; k0 < HH; k0 += BK) {
        float4 av[4], bv[4];
#pragma unroll
        for (int i = 0; i < 4; i++) {
            av[i] = *(const float4*)(A + (size_t)(m0 + rowT[i]) * HH + k0 + colT[i]);
            bv[i] = *(const float4*)(W + (size_t)(n0 + rowT[i]) * (2 * HH) + HH + k0 + colT[i]);
        }
        __syncthreads();
#pragma unroll
        for (int i = 0; i < 4; i++) {
            ushort4 ua = make_ushort4(f2bf(av[i].x), f2bf(av[i].y), f2bf(av[i].z), f2bf(av[i].w));
            ushort4 ub = make_ushort4(f2bf(bv[i].x), f2bf(bv[i].y), f2bf(bv[i].z), f2bf(bv[i].w));
            *(ushort4*)&As[rowT[i] * LDT + colT[i]] = ua;
            *(ushort4*)&Bs[rowT[i] * LDT + colT[i]] = ub;
        }
        __syncthreads();
        bf16x8 af[4], bf[4];
#pragma unroll
        for (int i = 0; i < 4; i++)
            af[i] = *(const bf16x8*)&As[(wm + i * 16 + l16) * LDT + quad * 8];
#pragma unroll
        for (int j = 0; j < 4; j++)
            bf[j] = *(const bf16x8*)&Bs[(wn + j * 16 + l16) * LDT + quad * 8];
#pragma unroll
        for (int i = 0; i < 4; i++)
#pragma unroll
            for (int j = 0; j < 4; j++)
                acc[i][j] = __builtin_amdgcn_mfma_f32_16x16x32_bf16(af[i], bf[j], acc[i][j], 0, 0, 0);
    }
    float ph[4], vv[4];
#pragma unroll
    for (int j = 0; j < 4; j++) {
        int ng = n0 + wn + j * 16 + l16;
        ph[j] = projh[bidx * HH + ng];
        vv[j] = vW[ng];
    }
#pragma unroll
    for (int i = 0; i < 4; i++) {
        float s[4] = {0.f, 0.f, 0.f, 0.f};
#pragma unroll
        for (int j = 0; j < 4; j++) {
#pragma unroll
            for (int r = 0; r < 4; r++) {
                float e = acc[i][j][r] + ph[j];
                e = e > 0.f ? e : 0.f;
                s[r] += e * vv[j];
            }
        }
#pragma unroll
        for (int r = 0; r < 4; r++) {
            s[r] += __shfl_xor(s[r], 1);
            s[r] += __shfl_xor(s[r], 2);
            s[r] += __shfl_xor(s[r], 4);
            s[r] += __shfl_xor(s[r], 8);
        }
        if (l16 == 0) {
#pragma unroll
            for (int r = 0; r < 4; r++) {
                int mg = m0 + wm + i * 16 + quad * 4 + r;
                atomicAdd(&scores[mg], s[r]);
            }
        }
    }
}

// ---------------- softmax over S per batch ----------------
__global__ __launch_bounds__(256) void softmax_kernel(
    const float* __restrict__ scores, float* __restrict__ wout)
{
    int b = blockIdx.x;
    int tid = threadIdx.x;
    const float* row = scores + b * SS;
    float x[8];
    float mx = -1e30f;
#pragma unroll
    for (int i = 0; i < 8; i++) { x[i] = row[tid + i * 256]; mx = fmaxf(mx, x[i]); }
#pragma unroll
    for (int off = 32; off; off >>= 1) mx = fmaxf(mx, __shfl_xor(mx, off));
    __shared__ float redm[4], reds[4];
    if ((tid & 63) == 0) redm[tid >> 6] = mx;
    __syncthreads();
    mx = fmaxf(fmaxf(redm[0], redm[1]), fmaxf(redm[2], redm[3]));
    float sum = 0.f;
#pragma unroll
    for (int i = 0; i < 8; i++) { x[i] = __expf(x[i] - mx); sum += x[i]; }
#pragma unroll
    for (int off = 32; off; off >>= 1) sum += __shfl_xor(sum, off);
    if ((tid & 63) == 0) reds[tid >> 6] = sum;
    __syncthreads();
    float inv = 1.0f / (reds[0] + reds[1] + reds[2] + reds[3]);
#pragma unroll
    for (int i = 0; i < 8; i++) wout[b * SS + tid + i * 256] = x[i] * inv;
}

// ---------------- context = weights @ a ----------------
__global__ __launch_bounds__(256) void context_kernel(
    const float* __restrict__ A, const float* __restrict__ wgt, float* __restrict__ ctx)
{
    int b = blockIdx.x >> 4;
    int sc = blockIdx.x & 15;
    int tid = threadIdx.x;
    const float* arow = A + ((size_t)b * SS + sc * 128) * HH + tid * 4;
    const float* wrow = wgt + b * SS + sc * 128;
    float4 acc = make_float4(0.f, 0.f, 0.f, 0.f);
#pragma unroll 4
    for (int s = 0; s < 128; s++) {
        float w = wrow[s];
        float4 v = *(const float4*)(arow + (size_t)s * HH);
        acc.x += w * v.x; acc.y += w * v.y; acc.z += w * v.z; acc.w += w * v.w;
    }
    float* o = ctx + b * HH + tid * 4;
    atomicAdd(o + 0, acc.x);
    atomicAdd(o + 1, acc.y);
    atomicAdd(o + 2, acc.z);
    atomicAdd(o + 3, acc.w);
}

extern "C" void kernel_launch(void* const* d_in, const int* in_sizes, int n_in,
                              void* d_out, int out_size, void* d_ws, size_t ws_size,
                              hipStream_t stream) {
    const float* h    = (const float*)d_in[0];
    // d_in[1] = c (unused by reference)
    const float* a    = (const float*)d_in[2];
    const float* W    = (const float*)d_in[3];
    const float* bias = (const float*)d_in[4];
    const float* vW   = (const float*)d_in[5];
    float* out = (float*)d_out;

    float* projh  = (float*)d_ws;              // 16384 f32  (64 KB)
    float* scores = projh + BB * HH;           // 32768 f32  (128 KB)
    __bf16* Wb = (__bf16*)(scores + MM);       // 1M bf16    (2 MB)
    __bf16* Ab = Wb + (size_t)HH * HH;         // 33.5M bf16 (67.1 MB)
    const size_t need = (size_t)(BB * HH + MM) * 4 + (size_t)HH * HH * 2
                      + (size_t)MM * HH * 2;

    if (ws_size >= need) {
        prep_kernel<<<336, 256, 0, stream>>>(h, W, bias, projh, Wb, scores, out);
        convert_A_kernel<<<(MM * HH / 8) / 256, 256, 0, stream>>>(a, Ab);
        gemm_scores_kernel<<<2048, 256, 0, stream>>>(Ab, Wb, projh, vW, scores);
    } else {
        prep_kernel<<<336, 256, 0, stream>>>(h, W, bias, projh, Wb, scores, out);
        gemm_scores_f32_kernel<<<dim3(HH / 128, MM / 128), 256, 0, stream>>>(a, W, projh, vW, scores);
    }

    softmax_kernel<<<BB, 256, 0, stream>>>(scores, out + BB * HH);
    context_kernel<<<BB * 16, 256, 0, stream>>>(a, out + BB * HH, out);
}